// Round 7
// baseline (155.679 us; speedup 1.0000x reference)
//
#include <hip/hip_runtime.h>
#include <math.h>

// Chamfer loss, B=32, N=2048, 3 used components.
// R7: R6 persistent-column structure + PACKED f32 math (v_pk_fma_f32 /
// v_pk_add_f32, full-rate on CDNA) + out-init folded into tile kernel
// (2 dispatches total, no memsets).
// Grid (16 bj, 2 half, 32 b) = 1024 blocks of 256 thr = 4 blocks/CU resident.
// Block holds 128 q-cols in registers; loops over 8 row-chunks of 128.
// Inner quad (2 row x 2 col pairs): rows packed in v2f lanes:
//   t{j} = pk_fma(px2, qx[j], pk_fma(py2, qy[j], pk_fma(pz2, qz[j], x22)))
//   col: min3(colacc[j], t.x, t.y)        (x2 folded, y2 deferred)
//   u{j} = t{j} + qw[j] (pk_add); row: min3(rowacc, u0.lane, u1.lane)
// = 6 pk_fma + 2 pk_add + 4 min3 per 4 pairs (3+eps instr/pair vs 5 scalar).
// Same math association as R6 (bit-identical result).
// ws: row partials ws_row[b][bi][bj][128] 4 MiB; col ws_col[b][bj][half][128]
// 512 KB (y2 folded). Finish: min 16 bj / 2 halves, sqrt, sum, atomicAdd.

#define NPTS   2048
#define NBATCH 32
#define NBI    16                      // row chunks of 128 (global index)
#define NBJ    16                      // col chunks of 128
#define NHALF  2
#define WS_ROW_FLOATS ((size_t)NBATCH * NBI * NBJ * 128)   // 1M floats = 4 MiB
#define EPSF   1e-16f
#define BIGF   3.4e38f

typedef float v2f __attribute__((ext_vector_type(2)));

__device__ __forceinline__ float min3f(float a, float b, float c) {
    return fminf(fminf(a, b), c);      // -> v_min3_f32
}

__global__ __launch_bounds__(256, 4) void chamfer_tile_kernel(
    const float* __restrict__ P, const float* __restrict__ Q,
    float* __restrict__ ws, float* __restrict__ out)
{
    __shared__ float4 sq[128];         // {-2x,-2y,-2z,|q|^2}
    __shared__ float  scol[4][128];    // per-wave col partials

    const int tid  = threadIdx.x;
    const int tx   = tid & 15;         // col group
    const int ty   = tid >> 4;         // row group 0..15
    const int lane = tid & 63;
    const int wv   = tid >> 6;
    const int bj   = blockIdx.x;       // col chunk (q)
    const int half = blockIdx.y;       // row half
    const int b    = blockIdx.z;       // batch

    // init output accumulator (finish kernel runs strictly after)
    if (bj == 0 && half == 0 && b == 0 && tid == 0) *out = 0.f;

    // ---- stage q tile to LDS once (threads 0..127, coalesced float4)
    if (tid < 128) {
        float4 qv = ((const float4*)Q)[(size_t)b * NPTS + bj * 128 + tid];
        sq[tid] = make_float4(-2.f * qv.y, -2.f * qv.z, -2.f * qv.w,
                              qv.y * qv.y + qv.z * qv.z + qv.w * qv.w);
    }
    __syncthreads();

    // ---- thread's 8 q cols c = tx + 16j -> unpacked registers
    float qx[8], qy[8], qz[8], qw[8], colacc[8];
    #pragma unroll
    for (int j = 0; j < 8; ++j) {
        float4 t = sq[tx + 16 * j];
        qx[j] = t.x; qy[j] = t.y; qz[j] = t.z; qw[j] = t.w;
        colacc[j] = BIGF;
    }

    const float4* Pb = (const float4*)P + (size_t)b * NPTS
                     + (size_t)half * (NPTS / 2);

    // ---- persistent loop over this half's 8 row chunks (NO barriers)
    for (int it = 0; it < 8; ++it) {
        const int bi = half * 8 + it;

        // 8 p rows r = ty + 16k, packed as row-pairs in v2f lanes
        v2f px2[4], py2[4], pz2[4], x22[4];
        float rowacc[8];
        #pragma unroll
        for (int k = 0; k < 8; ++k) {
            float4 v = Pb[it * 128 + ty + 16 * k];
            px2[k >> 1][k & 1] = v.y;
            py2[k >> 1][k & 1] = v.z;
            pz2[k >> 1][k & 1] = v.w;
            x22[k >> 1][k & 1] = fmaf(v.y, v.y, fmaf(v.z, v.z, v.w * v.w));
            rowacc[k] = BIGF;
        }

        // packed compute: 4 jp x 4 kk x (6 pk_fma + 2 pk_add + 4 min3)
        #pragma unroll
        for (int jp = 0; jp < 4; ++jp) {
            const int j0 = 2 * jp, j1 = j0 + 1;
            const v2f qx0 = {qx[j0], qx[j0]}, qy0 = {qy[j0], qy[j0]};
            const v2f qz0 = {qz[j0], qz[j0]}, qw0 = {qw[j0], qw[j0]};
            const v2f qx1 = {qx[j1], qx[j1]}, qy1 = {qy[j1], qy[j1]};
            const v2f qz1 = {qz[j1], qz[j1]}, qw1 = {qw[j1], qw[j1]};
            #pragma unroll
            for (int kk = 0; kk < 4; ++kk) {
                // t = dot' + x2 (x2 seeded into innermost fma) for rows 2kk,2kk+1
                v2f t0 = __builtin_elementwise_fma(px2[kk], qx0,
                         __builtin_elementwise_fma(py2[kk], qy0,
                         __builtin_elementwise_fma(pz2[kk], qz0, x22[kk])));
                v2f t1 = __builtin_elementwise_fma(px2[kk], qx1,
                         __builtin_elementwise_fma(py2[kk], qy1,
                         __builtin_elementwise_fma(pz2[kk], qz1, x22[kk])));
                // col: min over rows of t (y2 deferred to epilogue)
                colacc[j0] = min3f(colacc[j0], t0.x, t0.y);
                colacc[j1] = min3f(colacc[j1], t1.x, t1.y);
                // row: d2 = t + y2 (pk_add), then min across the two cols
                v2f u0 = t0 + qw0;
                v2f u1 = t1 + qw1;
                rowacc[2*kk]   = min3f(rowacc[2*kk],   u0.x, u1.x);
                rowacc[2*kk+1] = min3f(rowacc[2*kk+1], u0.y, u1.y);
            }
        }

        // row reduce over tx (lane bits 0..3); rowacc IS d2 already
        #pragma unroll
        for (int k = 0; k < 8; ++k) {
            float v = rowacc[k];
            v = fminf(v, __shfl_xor(v, 1));
            v = fminf(v, __shfl_xor(v, 2));
            v = fminf(v, __shfl_xor(v, 4));
            v = fminf(v, __shfl_xor(v, 8));
            rowacc[k] = v;
        }
        if (tx == 0) {
            float* rb = ws + (((size_t)b * NBI + bi) * NBJ + bj) * 128;
            #pragma unroll
            for (int k = 0; k < 8; ++k) rb[ty + 16 * k] = rowacc[k];
        }
    }

    // ---- col epilogue: reduce over ty (lane bits 4,5), cross-wave via LDS
    #pragma unroll
    for (int j = 0; j < 8; ++j) {
        float v = colacc[j];
        v = fminf(v, __shfl_xor(v, 16));
        v = fminf(v, __shfl_xor(v, 32));
        colacc[j] = v;
    }
    if (lane < 16) {                   // lane == tx representative
        #pragma unroll
        for (int j = 0; j < 8; ++j) scol[wv][j * 16 + lane] = colacc[j];
    }
    __syncthreads();
    if (tid < 128) {
        float v = fminf(fminf(scol[0][tid], scol[1][tid]),
                        fminf(scol[2][tid], scol[3][tid]));
        float* cb = ws + WS_ROW_FLOATS
                  + (((size_t)b * NBJ + bj) * NHALF + half) * 128;
        cb[tid] = v + sq[tid].w;       // fold y2 (min over halves commutes)
    }
}

__global__ __launch_bounds__(256) void chamfer_finish_kernel(
    const float* __restrict__ ws, float* __restrict__ out)
{
    __shared__ float rbuf[4];
    const int tid = threadIdx.x;
    const int i   = blockIdx.x * 256 + tid;   // 0..65535
    const int b   = i >> 11;
    const int e   = i & 2047;
    const int ch  = e >> 7;                    // chunk index 0..15
    const int el  = e & 127;                   // element in chunk

    // row side: min over 16 bj partials (coalesced in el)
    float s;
    {
        const float* rb = ws + ((size_t)(b * NBI + ch) * NBJ) * 128 + el;
        float v = BIGF;
        #pragma unroll
        for (int j = 0; j < NBJ; ++j) v = fminf(v, rb[j * 128]);
        s = sqrtf(fmaxf(v, 0.f) + EPSF);
    }
    // col side: min over 2 half partials (coalesced in el)
    {
        const float* cb = ws + WS_ROW_FLOATS
                        + ((size_t)(b * NBJ + ch) * NHALF) * 128 + el;
        float v = fminf(cb[0], cb[128]);
        s += sqrtf(fmaxf(v, 0.f) + EPSF);
    }

    #pragma unroll
    for (int off = 32; off > 0; off >>= 1) s += __shfl_down(s, off);
    if ((tid & 63) == 0) rbuf[tid >> 6] = s;
    __syncthreads();
    if (tid == 0)
        atomicAdd(out, 0.5f * ((rbuf[0] + rbuf[1]) + (rbuf[2] + rbuf[3])));
}

extern "C" void kernel_launch(void* const* d_in, const int* in_sizes, int n_in,
                              void* d_out, int out_size, void* d_ws, size_t ws_size,
                              hipStream_t stream) {
    const float* P = (const float*)d_in[0];   // p[0] = first 32*2048*4 floats
    const float* Q = (const float*)d_in[1];
    float* out = (float*)d_out;
    float* ws  = (float*)d_ws;                // uses 4.5 MiB

    dim3 grid(NBJ, NHALF, NBATCH);            // 16 x 2 x 32 = 1024 blocks
    chamfer_tile_kernel<<<grid, 256, 0, stream>>>(P, Q, ws, out);
    chamfer_finish_kernel<<<256, 256, 0, stream>>>(ws, out);
}

// Round 8
// 80.080 us; speedup vs baseline: 1.9440x; 1.9440x over previous
//
#include <hip/hip_runtime.h>
#include <math.h>

// Chamfer loss, B=32, N=2048, 3 used components.
// R8 = R2 champion (83.0 us, best replicated total) + two verified grafts:
//  (a) seeded-x2 trick (from R6, passed absmax 0.0): t = dot' + x2 via 3 fma
//      (x2 seeded innermost). Col candidate is t itself (NO +x2 add);
//      row candidate = t + y2 -> rowacc accumulates full d2 directly.
//      20 VALU per 2x2 quad = 5/pair (was 6/pair).
//  (b) out=0 folded into tile kernel (from R7, passed): one dispatch fewer.
// Structure identical to R2: grid (8,8,32)=2048 blocks, 256 thr, 256x256
// tile, thread = 16 rows x 16 cols, atomicMin on uint-cast clamped d2 in ws,
// sentinel memset 0x7F, sum kernel does 0.5 * sum sqrt(min + eps).

#define NPTS   2048
#define NBATCH 32
#define NTOT   (2 * NBATCH * NPTS)   // 131072 min slots
#define EPSF   1e-16f
#define BIGF   3.4e38f

__device__ __forceinline__ float min3f(float a, float b, float c) {
    return fminf(fminf(a, b), c);    // -> v_min3_f32
}

__global__ __launch_bounds__(256) void chamfer_tile_kernel(
    const float* __restrict__ P, const float* __restrict__ Q,
    unsigned int* __restrict__ ws, float* __restrict__ out)
{
    __shared__ float4 sp[256];        // {x, y, z, |p|^2}
    __shared__ float4 sq[256];        // {-2x, -2y, -2z, |q|^2}
    __shared__ float  scol[4][256];   // per-wave col partials

    const int tid = threadIdx.x;
    const int tx  = tid & 15;         // col group
    const int ty  = tid >> 4;         // row group (0..15, spans 4 waves)
    const int bi  = blockIdx.x;       // row chunk (p)
    const int bj  = blockIdx.y;      // col chunk (q)
    const int b   = blockIdx.z;       // batch

    // init output accumulator (sum kernel runs strictly after this kernel)
    if (bi == 0 && bj == 0 && b == 0 && tid == 0) *out = 0.f;

    // ---- stage tile points (1 float4 load each, coalesced)
    {
        float4 pv = ((const float4*)P)[(size_t)b * NPTS + bi * 256 + tid];
        sp[tid] = make_float4(pv.y, pv.z, pv.w,
                              pv.y*pv.y + pv.z*pv.z + pv.w*pv.w);
        float4 qv = ((const float4*)Q)[(size_t)b * NPTS + bj * 256 + tid];
        sq[tid] = make_float4(-2.f*qv.y, -2.f*qv.z, -2.f*qv.w,
                              qv.y*qv.y + qv.z*qv.z + qv.w*qv.w);
    }
    __syncthreads();

    // ---- thread's 16 p rows: r = ty + 16k (broadcast reads, conflict-free)
    float px[16], py[16], pz[16], x2[16];
    #pragma unroll
    for (int k = 0; k < 16; ++k) {
        float4 v = sp[ty + 16 * k];
        px[k] = v.x; py[k] = v.y; pz[k] = v.z; x2[k] = v.w;
    }

    float rowacc[16], colacc[16];
    #pragma unroll
    for (int k = 0; k < 16; ++k) { rowacc[k] = BIGF; colacc[k] = BIGF; }

    // ---- main loop: j-pairs over thread's 16 cols c = tx + 16j
    // t = dot' + x2 (x2 seeded into innermost fma).
    // row: min over m of (t + y2) == full d2.  col: min over n of t.
    for (int jp = 0; jp < 8; ++jp) {
        float4 q0 = sq[tx + 32 * jp];        // j0 = 2*jp
        float4 q1 = sq[tx + 32 * jp + 16];   // j1 = 2*jp+1
        float c0 = BIGF, c1 = BIGF;
        #pragma unroll
        for (int k = 0; k < 16; k += 2) {
            float t00 = fmaf(px[k],   q0.x, fmaf(py[k],   q0.y, fmaf(pz[k],   q0.z, x2[k])));
            float t01 = fmaf(px[k],   q1.x, fmaf(py[k],   q1.y, fmaf(pz[k],   q1.z, x2[k])));
            float t10 = fmaf(px[k+1], q0.x, fmaf(py[k+1], q0.y, fmaf(pz[k+1], q0.z, x2[k+1])));
            float t11 = fmaf(px[k+1], q1.x, fmaf(py[k+1], q1.y, fmaf(pz[k+1], q1.z, x2[k+1])));
            // row: d2 = t + y2
            rowacc[k]   = min3f(rowacc[k],   t00 + q0.w, t01 + q1.w);
            rowacc[k+1] = min3f(rowacc[k+1], t10 + q0.w, t11 + q1.w);
            // col: min over n of t (y2 folded in epilogue)
            c0 = min3f(c0, t00, t10);
            c1 = min3f(c1, t01, t11);
        }
        colacc[2*jp]     = c0;
        colacc[2*jp + 1] = c1;
    }

    // ---- row epilogue: reduce across tx (lane bits 0..3), publish
    #pragma unroll
    for (int k = 0; k < 16; ++k) {
        float v = rowacc[k];
        v = fminf(v, __shfl_xor(v, 1));
        v = fminf(v, __shfl_xor(v, 2));
        v = fminf(v, __shfl_xor(v, 4));
        v = fminf(v, __shfl_xor(v, 8));
        rowacc[k] = v;
    }
    if (tx == 0) {
        #pragma unroll
        for (int k = 0; k < 16; ++k) {
            float d2 = fmaxf(rowacc[k], 0.f);   // rowacc IS d2 already
            atomicMin(&ws[b * NPTS + bi * 256 + (ty + 16 * k)],
                      __float_as_uint(d2));
        }
    }

    // ---- col epilogue: reduce across ty. In-wave: lane bits 4,5.
    #pragma unroll
    for (int j = 0; j < 16; ++j) {
        float v = colacc[j];
        v = fminf(v, __shfl_xor(v, 16));
        v = fminf(v, __shfl_xor(v, 32));
        colacc[j] = v;
    }
    {
        const int wv   = tid >> 6;
        const int lane = tid & 63;
        if (lane < 16) {               // lane == tx, w_ty == 0
            #pragma unroll
            for (int j = 0; j < 16; ++j) scol[wv][j * 16 + lane] = colacc[j];
        }
    }
    __syncthreads();
    {
        const int c = tid;             // col index in tile; scol idx == c
        float v = fminf(fminf(scol[0][c], scol[1][c]),
                        fminf(scol[2][c], scol[3][c]));
        float d2 = fmaxf(v + sq[c].w, 0.f);     // fold y2 here
        atomicMin(&ws[NBATCH * NPTS + b * NPTS + bj * 256 + c],
                  __float_as_uint(d2));
    }
}

__global__ __launch_bounds__(256) void chamfer_sum_kernel(
    const unsigned int* __restrict__ ws, float* __restrict__ out)
{
    __shared__ float rbuf[4];
    const int tid = threadIdx.x;
    const int i0  = blockIdx.x * 256 + tid;

    float s = 0.f;
    for (int i = i0; i < NTOT; i += gridDim.x * 256)
        s += sqrtf(__uint_as_float(ws[i]) + EPSF);

    #pragma unroll
    for (int off = 32; off > 0; off >>= 1) s += __shfl_down(s, off);
    if ((tid & 63) == 0) rbuf[tid >> 6] = s;
    __syncthreads();
    if (tid == 0)
        atomicAdd(out, 0.5f * ((rbuf[0] + rbuf[1]) + (rbuf[2] + rbuf[3])));
}

extern "C" void kernel_launch(void* const* d_in, const int* in_sizes, int n_in,
                              void* d_out, int out_size, void* d_ws, size_t ws_size,
                              hipStream_t stream) {
    const float* P = (const float*)d_in[0];   // p[0] = first 32*2048*4 floats
    const float* Q = (const float*)d_in[1];
    float* out = (float*)d_out;
    unsigned int* ws = (unsigned int*)d_ws;

    // sentinel 0x7F7F7F7F = 3.39e38f (uint-monotone for nonneg floats)
    hipMemsetAsync(ws, 0x7F, (size_t)NTOT * sizeof(unsigned int), stream);

    dim3 grid(NPTS / 256, NPTS / 256, NBATCH);   // 8 x 8 x 32 = 2048 blocks
    chamfer_tile_kernel<<<grid, 256, 0, stream>>>(P, Q, ws, out);

    chamfer_sum_kernel<<<128, 256, 0, stream>>>(ws, out);
}